// Round 3
// baseline (125.376 us; speedup 1.0000x reference)
//
#include <hip/hip_runtime.h>
#include <math.h>
#include <stdint.h>

typedef short bf16x8 __attribute__((ext_vector_type(8)));   // 8 bf16 (4 VGPRs)
typedef float f32x4 __attribute__((ext_vector_type(4)));

#define NFRAGS 36
#define T 4                 // point-tiles (16 pts) per wave — 4 independent chains
#define NW 4                // waves per block
#define BS 256
#define PTS_BLK (NW * T * 16)   // 256 points per block-chunk
#define WBYTES (NFRAGS * 1024)  // 36 KB packed weights in LDS
#define ABYTES (NW * T * 1024)  // 16 KB activation staging
#define GRID_P 768              // persistent grid: 3 blocks/CU (LDS-limited)

// RNE float -> bf16 bits (prologue only; weights keep full rounding quality)
__device__ __forceinline__ uint32_t f2bf_rne(float f) {
    uint32_t u = __float_as_uint(f);
    return (u + 0x7FFFu + ((u >> 16) & 1u)) >> 16;
}

// ---- hot-path pack: TRUNCATING f32x2 -> packed bf16 in ONE v_perm ----
__device__ __forceinline__ uint32_t pk2(float a, float b) {
    return __builtin_amdgcn_perm(__float_as_uint(b), __float_as_uint(a), 0x07060302u);
}
// relu on packed bf16 pair (bf16 bits as i16: negative iff float negative)
__device__ __forceinline__ uint32_t relu2(uint32_t x) {
    uint32_t r;
    asm("v_pk_max_i16 %0, %1, 0" : "=v"(r) : "v"(x));
    return r;
}
__device__ __forceinline__ uint32_t pk2r(float a, float b) { return relu2(pk2(a, b)); }
__device__ __forceinline__ uint16_t bfu(float v) { return (uint16_t)(__float_as_uint(v) >> 16); }

// producer storage permutation: f = sperm(s), swap bits [5:4] <-> [3:2]
__device__ __forceinline__ int sperm(int k) {
    return (k & 3) | (((k >> 2) & 3) << 4) | (((k >> 4) & 3) << 2);
}
// register-transpose permutation: hw-k -> storage-s after 4x permlane32_swap
// s = {k5, k3, k4, k2, k1, k0}
__device__ __forceinline__ int rperm(int k) {
    return (k & 32) | (((k >> 3) & 1) << 4) | (((k >> 4) & 1) << 3) | (k & 7);
}

// ---------------- prologue: pack 36 A-fragments into d_ws ----------------
// pm=0: plain k (LDS-fed layers: ws0, wc0). pm=2: register-transpose-fed
// layers (ws1, ws2, wc1, wc2, wc3): weight at hw-k = W[sperm(rperm(k))].
__global__ void pack_weights(const float* __restrict__ ws0, const float* __restrict__ ws1,
                             const float* __restrict__ ws2, const float* __restrict__ wc0,
                             const float* __restrict__ wc1, const float* __restrict__ wc2,
                             const float* __restrict__ wc3, uint4* __restrict__ wpack) {
    int idx = blockIdx.x * blockDim.x + threadIdx.x;
    if (idx >= NFRAGS * 64) return;
    int F = idx >> 6, cl = idx & 63, cm = cl & 15, cq = cl >> 4;
    const float* w; int IN, OUT, mt, ks, pm;
    if (F < 4)       { w = ws0; IN = 3;  OUT = 64; mt = F;            ks = 0;          pm = 0; }
    else if (F < 12) { w = ws1; IN = 64; OUT = 64; mt = (F-4) >> 1;   ks = (F-4) & 1;  pm = 2; }
    else if (F < 14) { w = ws2; IN = 64; OUT = 16; mt = 0;            ks = F - 12;     pm = 2; }
    else if (F < 18) { w = wc0; IN = 18; OUT = 64; mt = F - 14;       ks = 0;          pm = 0; }
    else if (F < 26) { w = wc1; IN = 64; OUT = 64; mt = (F-18) >> 1;  ks = (F-18) & 1; pm = 2; }
    else if (F < 34) { w = wc2; IN = 64; OUT = 64; mt = (F-26) >> 1;  ks = (F-26) & 1; pm = 2; }
    else             { w = wc3; IN = 64; OUT = 3;  mt = 0;            ks = F - 34;     pm = 2; }
    const int fo = mt * 16 + cm;
    uint32_t pk[4];
    for (int jj = 0; jj < 4; ++jj) {
        uint32_t h[2];
        for (int bb = 0; bb < 2; ++bb) {
            int kg = ks * 32 + cq * 8 + jj * 2 + bb;      // hw k position
            int kr = (pm == 2) ? sperm(rperm(kg)) : kg;   // source feature index
            float v = 0.f;
            if (fo < OUT && kr < IN) v = w[kr * OUT + fo];
            h[bb] = f2bf_rne(v);
        }
        pk[jj] = h[0] | (h[1] << 16);
    }
    wpack[F * 64 + cl] = make_uint4(pk[0], pk[1], pk[2], pk[3]);
}

// ---------------- main kernel ----------------
// Persistent-block revision:
//  * all 36 weight fragments staged to LDS once per block; per-layer loads
//    are ds_read_b128 with folded immediate offsets (no vmcnt layer-head
//    stalls, no 64-bit address VALU)
//  * grid-stride chunk loop; next chunk's x is loaded during the current
//    chunk's compute (hides ~900cy HBM latency)
//  * T=4 tiles/wave amortizes fixed per-task cost; activation staging
//    compacted to 1KB/tile (granules 4..7 were never used)
// launch_bounds(BS,4): 128-VGPR budget. NEVER request more waves/EU here:
// earlier (,8) capped VGPR at 32 -> 1.2 GB scratch spill, 7x regression.
__global__ __launch_bounds__(BS, 4) void nerf_main(const float* __restrict__ xin,
                                                   const uint4* __restrict__ wpack,
                                                   float* __restrict__ outp,
                                                   int n, int nchunks) {
    __shared__ __align__(16) char smem[WBYTES + ABYTES];
    const int tid = threadIdx.x, wv = tid >> 6, lane = tid & 63;
    const int p = lane & 15, q = lane >> 4;

    // ---- stage packed weights into LDS (once per persistent block) ----
    {
        uint4* wl = (uint4*)smem;
        const uint4* __restrict__ ws = wpack;
#pragma unroll
        for (int i = 0; i < (NFRAGS * 64) / BS; ++i)     // 9 x 16B per thread
            wl[tid + i * BS] = ws[tid + i * BS];
    }

    char* wbase = smem + lane * 16;
    auto ldW = [&](int F) -> bf16x8 {                    // ds_read_b128 offset:F*1024
        return *(const bf16x8*)(wbase + F * 1024);
    };

    // activation staging: 1KB per tile, 64B per point-row, 4 granules of 16B
    char* actp = smem + WBYTES + wv * (T * 1024) + p * 64;
    auto aaddr = [&](int t, int g) -> char* {
        return actp + t * 1024 + (((g ^ (p & 3))) << 4);
    };
    const f32x4 z4 = {0.f, 0.f, 0.f, 0.f};

    // D (4 m-tiles) -> pack+relu -> 4x v_permlane32_swap -> next layer's B frags.
    auto xpose = [&](const f32x4* d, bf16x8& b0, bf16x8& b1) {
        uint32_t X0 = pk2r(d[0][0], d[0][1]), X1 = pk2r(d[0][2], d[0][3]);
        uint32_t X2 = pk2r(d[1][0], d[1][1]), X3 = pk2r(d[1][2], d[1][3]);
        uint32_t X4 = pk2r(d[2][0], d[2][1]), X5 = pk2r(d[2][2], d[2][3]);
        uint32_t X6 = pk2r(d[3][0], d[3][1]), X7 = pk2r(d[3][2], d[3][3]);
        asm("v_permlane32_swap_b32 %0, %1" : "+v"(X0), "+v"(X4));
        asm("v_permlane32_swap_b32 %0, %1" : "+v"(X1), "+v"(X5));
        asm("v_permlane32_swap_b32 %0, %1" : "+v"(X2), "+v"(X6));
        asm("v_permlane32_swap_b32 %0, %1" : "+v"(X3), "+v"(X7));
        uint4 u0 = make_uint4(X0, X1, X2, X3), u1 = make_uint4(X4, X5, X6, X7);
        b0 = *(bf16x8*)&u0; b1 = *(bf16x8*)&u1;
    };

    bf16x8 c0[T], c1[T];   // live activation fragments (register path)

    // K=32 LDS-fed layer (L0: ws0, L3: wc0) — per-tile xpose
    auto layerK32 = [&](int FB) {
        bf16x8 W0 = ldW(FB), W1 = ldW(FB + 1), W2 = ldW(FB + 2), W3 = ldW(FB + 3);
#pragma unroll
        for (int t = 0; t < T; ++t) {
            bf16x8 b = *(const bf16x8*)aaddr(t, q);
            f32x4 d[4];
            d[0] = __builtin_amdgcn_mfma_f32_16x16x32_bf16(W0, b, z4, 0, 0, 0);
            d[1] = __builtin_amdgcn_mfma_f32_16x16x32_bf16(W1, b, z4, 0, 0, 0);
            d[2] = __builtin_amdgcn_mfma_f32_16x16x32_bf16(W2, b, z4, 0, 0, 0);
            d[3] = __builtin_amdgcn_mfma_f32_16x16x32_bf16(W3, b, z4, 0, 0, 0);
            xpose(d, c0[t], c1[t]);
        }
    };

    // 64->64 register-fed layer — per-tile xpose (short d lifetime)
    auto layer64 = [&](int FB) {
        bf16x8 W[8];
#pragma unroll
        for (int i = 0; i < 8; ++i) W[i] = ldW(FB + i);
#pragma unroll
        for (int t = 0; t < T; ++t) {
            f32x4 d[4];
#pragma unroll
            for (int mt = 0; mt < 4; ++mt) {
                f32x4 acc = __builtin_amdgcn_mfma_f32_16x16x32_bf16(W[mt*2],   c0[t], z4,  0, 0, 0);
                d[mt]     = __builtin_amdgcn_mfma_f32_16x16x32_bf16(W[mt*2+1], c1[t], acc, 0, 0, 0);
            }
            xpose(d, c0[t], c1[t]);
        }
    };

    // ---- prologue x load for first chunk (overlaps weight staging) ----
    int chunk = blockIdx.x;
    float2 xa = {0.f, 0.f}, xb = {0.f, 0.f}, xc = {0.f, 0.f};
    if (chunk < nchunks) {
        const int pi = chunk * PTS_BLK + wv * (T * 16) + q * 16 + p;
        if (pi < n) {
            const float2* xp = (const float2*)(xin + (size_t)pi * 6);
            xa = xp[0]; xb = xp[1]; xc = xp[2];
        }
    }

    __syncthreads();   // weights visible to all waves

    for (; chunk < nchunks; chunk += gridDim.x) {
        const int base = chunk * PTS_BLK + wv * (T * 16);
        const float vv0 = xb.y, vv1 = xc.x, vv2 = xc.y;

        // ---- stage current x: lane (p,q) owns tile q, point base+q*16+p ----
        *(uint4*)aaddr(q, 0) = make_uint4(pk2(xa.x, xa.y), pk2(xb.x, 0.f), 0u, 0u);
        *(uint4*)aaddr(q, 1) = make_uint4(0u, 0u, 0u, 0u);
        *(uint4*)aaddr(q, 2) = make_uint4(0u, 0u, 0u, 0u);
        *(uint4*)aaddr(q, 3) = make_uint4(0u, 0u, 0u, 0u);

        // ---- issue next chunk's x loads (hide HBM latency under compute) ----
        const int nc = chunk + gridDim.x;
        float2 na = {0.f, 0.f}, nb = {0.f, 0.f}, ncv = {0.f, 0.f};
        if (nc < nchunks) {
            const int pi2 = nc * PTS_BLK + wv * (T * 16) + q * 16 + p;
            if (pi2 < n) {
                const float2* xp2 = (const float2*)(xin + (size_t)pi2 * 6);
                na = xp2[0]; nb = xp2[1]; ncv = xp2[2];
            }
        }

        // ---- L0: sigma net 3->64 (frags 0..3), LDS-fed ----
        layerK32(0);

        // ---- L1: sigma net 64->64 (frags 4..11) ----
        layer64(4);

        // ---- L2: ws2 64->16 (frags 12,13): sigma + color-input assembly ----
        float sig[T];
        {
            bf16x8 A0 = ldW(12), A1 = ldW(13);
#pragma unroll
            for (int t = 0; t < T; ++t) {
                f32x4 acc = __builtin_amdgcn_mfma_f32_16x16x32_bf16(A0, c0[t], z4,  0, 0, 0);
                f32x4 d   = __builtin_amdgcn_mfma_f32_16x16x32_bf16(A1, c1[t], acc, 0, 0, 0);
                const float sx = d[0];                   // feat0 valid on q==0 lanes
                sig[t] = fmaxf(sx, 0.f) + __logf(1.f + __expf(-fabsf(sx)));
                // zero granules 0..3 collectively, then scatter (plain s = k layout)
                *(uint4*)aaddr(t, q) = make_uint4(0u, 0u, 0u, 0u);
                if (q == t) {   // views of point p, tile t live on lane (p, t)
                    *(uint32_t*)(aaddr(t, 0) + 0) = pk2(vv0, vv1);
                    *(uint16_t*)(aaddr(t, 0) + 4) = bfu(vv2);
                }
                // geo feats f=4q+r (f>=1) -> color k=f+2
                if (q == 0) {
                    *(uint16_t*)(aaddr(t, 0) + 6) = bfu(d[1]);
                    *(uint32_t*)(aaddr(t, 0) + 8) = pk2(d[2], d[3]);
                } else if (q == 1) {
                    *(uint32_t*)(aaddr(t, 0) + 12) = pk2(d[0], d[1]);
                    *(uint32_t*)(aaddr(t, 1) + 0)  = pk2(d[2], d[3]);
                } else if (q == 2) {
                    *(uint32_t*)(aaddr(t, 1) + 4) = pk2(d[0], d[1]);
                    *(uint32_t*)(aaddr(t, 1) + 8) = pk2(d[2], d[3]);
                } else {
                    *(uint32_t*)(aaddr(t, 1) + 12) = pk2(d[0], d[1]);
                    *(uint32_t*)(aaddr(t, 2) + 0)  = pk2(d[2], d[3]);
                }
            }
        }

        // ---- L3: wc0 18->64 (frags 14..17), LDS-fed ----
        layerK32(14);

        // ---- L4, L5: wc1, wc2 64->64 ----
        layer64(18);
        layer64(26);

        // ---- L6: wc3 64->3 (frags 34,35) + output ----
        {
            bf16x8 A0 = ldW(34), A1 = ldW(35);
#pragma unroll
            for (int t = 0; t < T; ++t) {
                f32x4 acc = __builtin_amdgcn_mfma_f32_16x16x32_bf16(A0, c0[t], z4,  0, 0, 0);
                f32x4 d   = __builtin_amdgcn_mfma_f32_16x16x32_bf16(A1, c1[t], acc, 0, 0, 0);
                if (q == 0) {
                    const int pt = base + t * 16 + p;
                    if (pt < n)
                        *(float4*)(outp + (size_t)pt * 4) = make_float4(d[0], d[1], d[2], sig[t]);
                }
            }
        }

        xa = na; xb = nb; xc = ncv;
    }
}

extern "C" void kernel_launch(void* const* d_in, const int* in_sizes, int n_in,
                              void* d_out, int out_size, void* d_ws, size_t ws_size,
                              hipStream_t stream) {
    const float* x   = (const float*)d_in[0];
    const float* ws0 = (const float*)d_in[1];
    const float* ws1 = (const float*)d_in[2];
    const float* ws2 = (const float*)d_in[3];
    const float* wc0 = (const float*)d_in[4];
    const float* wc1 = (const float*)d_in[5];
    const float* wc2 = (const float*)d_in[6];
    const float* wc3 = (const float*)d_in[7];
    float* out = (float*)d_out;
    uint4* wpack = (uint4*)d_ws;

    const int n = in_sizes[0] / 6;
    pack_weights<<<(NFRAGS * 64 + 255) / 256, 256, 0, stream>>>(ws0, ws1, ws2, wc0, wc1, wc2, wc3, wpack);
    const int nchunks = (n + PTS_BLK - 1) / PTS_BLK;
    const int grid = nchunks < GRID_P ? nchunks : GRID_P;
    nerf_main<<<grid, BS, 0, stream>>>(x, wpack, out, n, nchunks);
}

// Round 4
// 116.376 us; speedup vs baseline: 1.0773x; 1.0773x over previous
//
#include <hip/hip_runtime.h>
#include <math.h>
#include <stdint.h>

typedef short bf16x8 __attribute__((ext_vector_type(8)));   // 8 bf16 (4 VGPRs)
typedef float f32x4 __attribute__((ext_vector_type(4)));

#define NFRAGS 36
#define T 4                 // point-tiles (16 pts) per wave — 4 independent chains
#define NW 4                // waves per block
#define BS 256
#define PTS_BLK (NW * T * 16)   // 256 points per block

// RNE float -> bf16 bits (prologue only; weights keep full rounding quality)
__device__ __forceinline__ uint32_t f2bf_rne(float f) {
    uint32_t u = __float_as_uint(f);
    return (u + 0x7FFFu + ((u >> 16) & 1u)) >> 16;
}

// ---- hot-path pack: TRUNCATING f32x2 -> packed bf16 in ONE v_perm ----
__device__ __forceinline__ uint32_t pk2(float a, float b) {
    return __builtin_amdgcn_perm(__float_as_uint(b), __float_as_uint(a), 0x07060302u);
}
// relu on packed bf16 pair (bf16 bits as i16: negative iff float negative)
__device__ __forceinline__ uint32_t relu2(uint32_t x) {
    uint32_t r;
    asm("v_pk_max_i16 %0, %1, 0" : "=v"(r) : "v"(x));
    return r;
}
__device__ __forceinline__ uint32_t pk2r(float a, float b) { return relu2(pk2(a, b)); }
__device__ __forceinline__ uint16_t bfu(float v) { return (uint16_t)(__float_as_uint(v) >> 16); }

// producer storage permutation: f = sperm(s), swap bits [5:4] <-> [3:2]
__device__ __forceinline__ int sperm(int k) {
    return (k & 3) | (((k >> 2) & 3) << 4) | (((k >> 4) & 3) << 2);
}
// register-transpose permutation: hw-k -> storage-s after 4x permlane32_swap
// s = {k5, k3, k4, k2, k1, k0}
__device__ __forceinline__ int rperm(int k) {
    return (k & 32) | (((k >> 3) & 1) << 4) | (((k >> 4) & 1) << 3) | (k & 7);
}

// ---------------- prologue: pack 36 A-fragments into d_ws ----------------
// pm=0: plain k (LDS-fed layers: ws0, wc0). pm=2: register-transpose-fed
// layers (ws1, ws2, wc1, wc2, wc3): weight at hw-k = W[sperm(rperm(k))].
__global__ void pack_weights(const float* __restrict__ ws0, const float* __restrict__ ws1,
                             const float* __restrict__ ws2, const float* __restrict__ wc0,
                             const float* __restrict__ wc1, const float* __restrict__ wc2,
                             const float* __restrict__ wc3, uint4* __restrict__ wpack) {
    int idx = blockIdx.x * blockDim.x + threadIdx.x;
    if (idx >= NFRAGS * 64) return;
    int F = idx >> 6, cl = idx & 63, cm = cl & 15, cq = cl >> 4;
    const float* w; int IN, OUT, mt, ks, pm;
    if (F < 4)       { w = ws0; IN = 3;  OUT = 64; mt = F;            ks = 0;          pm = 0; }
    else if (F < 12) { w = ws1; IN = 64; OUT = 64; mt = (F-4) >> 1;   ks = (F-4) & 1;  pm = 2; }
    else if (F < 14) { w = ws2; IN = 64; OUT = 16; mt = 0;            ks = F - 12;     pm = 2; }
    else if (F < 18) { w = wc0; IN = 18; OUT = 64; mt = F - 14;       ks = 0;          pm = 0; }
    else if (F < 26) { w = wc1; IN = 64; OUT = 64; mt = (F-18) >> 1;  ks = (F-18) & 1; pm = 2; }
    else if (F < 34) { w = wc2; IN = 64; OUT = 64; mt = (F-26) >> 1;  ks = (F-26) & 1; pm = 2; }
    else             { w = wc3; IN = 64; OUT = 3;  mt = 0;            ks = F - 34;     pm = 2; }
    const int fo = mt * 16 + cm;
    uint32_t pk[4];
    for (int jj = 0; jj < 4; ++jj) {
        uint32_t h[2];
        for (int bb = 0; bb < 2; ++bb) {
            int kg = ks * 32 + cq * 8 + jj * 2 + bb;      // hw k position
            int kr = (pm == 2) ? sperm(rperm(kg)) : kg;   // source feature index
            float v = 0.f;
            if (fo < OUT && kr < IN) v = w[kr * OUT + fo];
            h[bb] = f2bf_rne(v);
        }
        pk[jj] = h[0] | (h[1] << 16);
    }
    wpack[F * 64 + cl] = make_uint4(pk[0], pk[1], pk[2], pk[3]);
}

// ---------------- main kernel ----------------
// R4: back to the R0 structure (global weight loads, one chunk per block,
// 2KB/tile 8-granule activation swizzle — the best-measured base at 48 µs).
// Levers on top:
//  * T=4 point-tiles/wave: amortizes the 36 A-frag loads + block prologue
//    over 33% more points; all 4 lane-quadrants stage (no q<T guard).
//  * s_setprio(1) around the 8-MFMA clusters of the 64->64 layers: waves in
//    their MFMA phase preempt co-resident waves doing xpose VALU (structure
//    matches the attn positive case: independent waves at different phases).
// launch_bounds(BS,4): 128-VGPR budget. NEVER request more waves/EU here:
// an earlier (,8) capped VGPR at 32 -> 1.2 GB scratch spill, 7x regression.
// LDS-weights + persistent blocks measured WORSE (51.5 µs, R3): occupancy
// tail + bank conflicts ate the layer-head-latency gain. Do not revisit.
__global__ __launch_bounds__(BS, 4) void nerf_main(const float* __restrict__ xin,
                                                   const uint4* __restrict__ wpack,
                                                   float* __restrict__ outp, int n) {
    // LDS only for input staging and the L2 color-input assembly.
    __shared__ __align__(16) char smem[NW * T * 2048];
    const int tid = threadIdx.x, wv = tid >> 6, lane = tid & 63;
    const int p = lane & 15, q = lane >> 4;
    const int sw = p & 7;
    char* actw = smem + wv * (T * 2048);
    const int base = blockIdx.x * PTS_BLK + wv * (T * 16);

    // inline address only (R5 lesson: runtime-indexed pointer arrays -> scratch)
    auto aaddr = [&](int t, int g) -> char* {
        return actw + t * 2048 + p * 128 + ((g ^ sw) << 4);
    };
    auto ldA = [&](int F) -> bf16x8 {
        uint4 u = wpack[F * 64 + lane];
        return *(bf16x8*)&u;
    };
    const f32x4 z4 = {0.f, 0.f, 0.f, 0.f};

    // D (4 m-tiles) -> pack+relu -> 4x v_permlane32_swap -> next layer's B frags.
    auto xpose = [&](const f32x4* d, bf16x8& b0, bf16x8& b1) {
        uint32_t X0 = pk2r(d[0][0], d[0][1]), X1 = pk2r(d[0][2], d[0][3]);
        uint32_t X2 = pk2r(d[1][0], d[1][1]), X3 = pk2r(d[1][2], d[1][3]);
        uint32_t X4 = pk2r(d[2][0], d[2][1]), X5 = pk2r(d[2][2], d[2][3]);
        uint32_t X6 = pk2r(d[3][0], d[3][1]), X7 = pk2r(d[3][2], d[3][3]);
        asm("v_permlane32_swap_b32 %0, %1" : "+v"(X0), "+v"(X4));
        asm("v_permlane32_swap_b32 %0, %1" : "+v"(X1), "+v"(X5));
        asm("v_permlane32_swap_b32 %0, %1" : "+v"(X2), "+v"(X6));
        asm("v_permlane32_swap_b32 %0, %1" : "+v"(X3), "+v"(X7));
        uint4 u0 = make_uint4(X0, X1, X2, X3), u1 = make_uint4(X4, X5, X6, X7);
        b0 = *(bf16x8*)&u0; b1 = *(bf16x8*)&u1;
    };

    // ---- staging: lane (p,q) stages tile q, point base+q*16+p ----
    float vv0 = 0.f, vv1 = 0.f, vv2 = 0.f;
    {
        float x0 = 0.f, x1 = 0.f, x2 = 0.f;
        const int pi = base + q * 16 + p;
        if (pi < n) {
            const float2* xp = (const float2*)(xin + (size_t)pi * 6);
            float2 a = xp[0], b = xp[1], c = xp[2];
            x0 = a.x; x1 = a.y; x2 = b.x; vv0 = b.y; vv1 = c.x; vv2 = c.y;
        }
        *(uint4*)aaddr(q, 0) = make_uint4(pk2(x0, x1), pk2(x2, 0.f), 0u, 0u);
        *(uint4*)aaddr(q, 1) = make_uint4(0u, 0u, 0u, 0u);
        *(uint4*)aaddr(q, 2) = make_uint4(0u, 0u, 0u, 0u);
        *(uint4*)aaddr(q, 3) = make_uint4(0u, 0u, 0u, 0u);
    }

    bf16x8 c0[T], c1[T];   // live activation fragments (register path)

    // K=32 LDS-fed layer (L0: ws0, L3: wc0) — per-tile xpose
    auto layerK32 = [&](int FB) {
        bf16x8 W0 = ldA(FB), W1 = ldA(FB + 1), W2 = ldA(FB + 2), W3 = ldA(FB + 3);
#pragma unroll
        for (int t = 0; t < T; ++t) {
            bf16x8 b = *(const bf16x8*)aaddr(t, q);
            f32x4 d[4];
            d[0] = __builtin_amdgcn_mfma_f32_16x16x32_bf16(W0, b, z4, 0, 0, 0);
            d[1] = __builtin_amdgcn_mfma_f32_16x16x32_bf16(W1, b, z4, 0, 0, 0);
            d[2] = __builtin_amdgcn_mfma_f32_16x16x32_bf16(W2, b, z4, 0, 0, 0);
            d[3] = __builtin_amdgcn_mfma_f32_16x16x32_bf16(W3, b, z4, 0, 0, 0);
            xpose(d, c0[t], c1[t]);
        }
    };

    // 64->64 register-fed layer — per-tile xpose, MFMA cluster under setprio
    auto layer64 = [&](int FB) {
        bf16x8 W[8];
#pragma unroll
        for (int i = 0; i < 8; ++i) W[i] = ldA(FB + i);
#pragma unroll
        for (int t = 0; t < T; ++t) {
            f32x4 d[4];
            __builtin_amdgcn_s_setprio(1);
#pragma unroll
            for (int mt = 0; mt < 4; ++mt) {
                f32x4 acc = __builtin_amdgcn_mfma_f32_16x16x32_bf16(W[mt*2],   c0[t], z4,  0, 0, 0);
                d[mt]     = __builtin_amdgcn_mfma_f32_16x16x32_bf16(W[mt*2+1], c1[t], acc, 0, 0, 0);
            }
            __builtin_amdgcn_s_setprio(0);
            xpose(d, c0[t], c1[t]);
        }
    };

    // ---- L0: sigma net 3->64 (frags 0..3), LDS-fed ----
    layerK32(0);

    // ---- L1: sigma net 64->64 (frags 4..11) ----
    layer64(4);

    // ---- L2: ws2 64->16 (frags 12,13): sigma + color-input assembly (LDS) ----
    float sig[T];
    {
        bf16x8 A0 = ldA(12), A1 = ldA(13);
#pragma unroll
        for (int t = 0; t < T; ++t) {
            f32x4 acc = __builtin_amdgcn_mfma_f32_16x16x32_bf16(A0, c0[t], z4,  0, 0, 0);
            f32x4 d   = __builtin_amdgcn_mfma_f32_16x16x32_bf16(A1, c1[t], acc, 0, 0, 0);
            const float sx = d[0];                       // feat0 valid on q==0 lanes
            sig[t] = fmaxf(sx, 0.f) + __logf(1.f + __expf(-fabsf(sx)));
            // zero granules 0..3 collectively, then scatter (plain s = k layout)
            *(uint4*)aaddr(t, q) = make_uint4(0u, 0u, 0u, 0u);
            if (q == t) {   // views of point p, tile t live on lane (p, t)
                *(uint32_t*)(aaddr(t, 0) + 0) = pk2(vv0, vv1);
                *(uint16_t*)(aaddr(t, 0) + 4) = bfu(vv2);
            }
            // geo feats f=4q+r (f>=1) -> color k=f+2
            if (q == 0) {
                *(uint16_t*)(aaddr(t, 0) + 6) = bfu(d[1]);
                *(uint32_t*)(aaddr(t, 0) + 8) = pk2(d[2], d[3]);
            } else if (q == 1) {
                *(uint32_t*)(aaddr(t, 0) + 12) = pk2(d[0], d[1]);
                *(uint32_t*)(aaddr(t, 1) + 0)  = pk2(d[2], d[3]);
            } else if (q == 2) {
                *(uint32_t*)(aaddr(t, 1) + 4) = pk2(d[0], d[1]);
                *(uint32_t*)(aaddr(t, 1) + 8) = pk2(d[2], d[3]);
            } else {
                *(uint32_t*)(aaddr(t, 1) + 12) = pk2(d[0], d[1]);
                *(uint32_t*)(aaddr(t, 2) + 0)  = pk2(d[2], d[3]);
            }
        }
    }

    // ---- L3: wc0 18->64 (frags 14..17), LDS-fed ----
    layerK32(14);

    // ---- L4, L5: wc1, wc2 64->64 ----
    layer64(18);
    layer64(26);

    // ---- L6: wc3 64->3 (frags 34,35) + output ----
    {
        bf16x8 A0 = ldA(34), A1 = ldA(35);
#pragma unroll
        for (int t = 0; t < T; ++t) {
            f32x4 acc = __builtin_amdgcn_mfma_f32_16x16x32_bf16(A0, c0[t], z4,  0, 0, 0);
            f32x4 d   = __builtin_amdgcn_mfma_f32_16x16x32_bf16(A1, c1[t], acc, 0, 0, 0);
            if (q == 0) {
                const int pt = base + t * 16 + p;
                if (pt < n)
                    *(float4*)(outp + (size_t)pt * 4) = make_float4(d[0], d[1], d[2], sig[t]);
            }
        }
    }
}

extern "C" void kernel_launch(void* const* d_in, const int* in_sizes, int n_in,
                              void* d_out, int out_size, void* d_ws, size_t ws_size,
                              hipStream_t stream) {
    const float* x   = (const float*)d_in[0];
    const float* ws0 = (const float*)d_in[1];
    const float* ws1 = (const float*)d_in[2];
    const float* ws2 = (const float*)d_in[3];
    const float* wc0 = (const float*)d_in[4];
    const float* wc1 = (const float*)d_in[5];
    const float* wc2 = (const float*)d_in[6];
    const float* wc3 = (const float*)d_in[7];
    float* out = (float*)d_out;
    uint4* wpack = (uint4*)d_ws;

    const int n = in_sizes[0] / 6;
    pack_weights<<<(NFRAGS * 64 + 255) / 256, 256, 0, stream>>>(ws0, ws1, ws2, wc0, wc1, wc2, wc3, wpack);
    const int grid = (n + PTS_BLK - 1) / PTS_BLK;
    nerf_main<<<grid, BS, 0, stream>>>(x, wpack, out, n);
}

// Round 5
// 114.760 us; speedup vs baseline: 1.0925x; 1.0141x over previous
//
#include <hip/hip_runtime.h>
#include <math.h>
#include <stdint.h>

typedef short bf16x8 __attribute__((ext_vector_type(8)));   // 8 bf16 (4 VGPRs)
typedef float f32x4 __attribute__((ext_vector_type(4)));

#define NFRAGS 36
#define T 4                 // point-tiles (16 pts) per wave — 4 independent chains
#define NW 4                // waves per block
#define BS 256
#define PTS_BLK (NW * T * 16)   // 256 points per block

// RNE float -> bf16 bits (prologue only; weights keep full rounding quality)
__device__ __forceinline__ uint32_t f2bf_rne(float f) {
    uint32_t u = __float_as_uint(f);
    return (u + 0x7FFFu + ((u >> 16) & 1u)) >> 16;
}

// ---- hot-path pack: TRUNCATING f32x2 -> packed bf16 in ONE v_perm ----
__device__ __forceinline__ uint32_t pk2(float a, float b) {
    return __builtin_amdgcn_perm(__float_as_uint(b), __float_as_uint(a), 0x07060302u);
}
// relu on packed bf16 pair (bf16 bits as i16: negative iff float negative)
__device__ __forceinline__ uint32_t relu2(uint32_t x) {
    uint32_t r;
    asm("v_pk_max_i16 %0, %1, 0" : "=v"(r) : "v"(x));
    return r;
}
__device__ __forceinline__ uint32_t pk2r(float a, float b) { return relu2(pk2(a, b)); }
__device__ __forceinline__ uint16_t bfu(float v) { return (uint16_t)(__float_as_uint(v) >> 16); }

// producer storage permutation: f = sperm(s), swap bits [5:4] <-> [3:2]
__device__ __forceinline__ int sperm(int k) {
    return (k & 3) | (((k >> 2) & 3) << 4) | (((k >> 4) & 3) << 2);
}
// register-transpose permutation: hw-k -> storage-s after 4x permlane32_swap
// s = {k5, k3, k4, k2, k1, k0}
__device__ __forceinline__ int rperm(int k) {
    return (k & 32) | (((k >> 3) & 1) << 4) | (((k >> 4) & 1) << 3) | (k & 7);
}

// ---------------- prologue: pack 36 A-fragments into d_ws ----------------
// pm=0: plain k (LDS-fed layers: ws0, wc0). pm=2: register-transpose-fed
// layers (ws1, ws2, wc1, wc2, wc3): weight at hw-k = W[sperm(rperm(k))].
__global__ void pack_weights(const float* __restrict__ ws0, const float* __restrict__ ws1,
                             const float* __restrict__ ws2, const float* __restrict__ wc0,
                             const float* __restrict__ wc1, const float* __restrict__ wc2,
                             const float* __restrict__ wc3, uint4* __restrict__ wpack) {
    int idx = blockIdx.x * blockDim.x + threadIdx.x;
    if (idx >= NFRAGS * 64) return;
    int F = idx >> 6, cl = idx & 63, cm = cl & 15, cq = cl >> 4;
    const float* w; int IN, OUT, mt, ks, pm;
    if (F < 4)       { w = ws0; IN = 3;  OUT = 64; mt = F;            ks = 0;          pm = 0; }
    else if (F < 12) { w = ws1; IN = 64; OUT = 64; mt = (F-4) >> 1;   ks = (F-4) & 1;  pm = 2; }
    else if (F < 14) { w = ws2; IN = 64; OUT = 16; mt = 0;            ks = F - 12;     pm = 2; }
    else if (F < 18) { w = wc0; IN = 18; OUT = 64; mt = F - 14;       ks = 0;          pm = 0; }
    else if (F < 26) { w = wc1; IN = 64; OUT = 64; mt = (F-18) >> 1;  ks = (F-18) & 1; pm = 2; }
    else if (F < 34) { w = wc2; IN = 64; OUT = 64; mt = (F-26) >> 1;  ks = (F-26) & 1; pm = 2; }
    else             { w = wc3; IN = 64; OUT = 3;  mt = 0;            ks = F - 34;     pm = 2; }
    const int fo = mt * 16 + cm;
    uint32_t pk[4];
    for (int jj = 0; jj < 4; ++jj) {
        uint32_t h[2];
        for (int bb = 0; bb < 2; ++bb) {
            int kg = ks * 32 + cq * 8 + jj * 2 + bb;      // hw k position
            int kr = (pm == 2) ? sperm(rperm(kg)) : kg;   // source feature index
            float v = 0.f;
            if (fo < OUT && kr < IN) v = w[kr * OUT + fo];
            h[bb] = f2bf_rne(v);
        }
        pk[jj] = h[0] | (h[1] << 16);
    }
    wpack[F * 64 + cl] = make_uint4(pk[0], pk[1], pk[2], pk[3]);
}

// ---------------- main kernel ----------------
// R5: R4 structure (global weight loads, T=4, setprio on MFMA clusters)
// with PAIRED-TILE LDS: activation tiles only ever used granules 0..3
// (64B of each 128B row), so tiles t and t^1 now share one 2KB region —
// tile t granule g sits at swizzled slot (g ^ 4(t&1)) ^ (p&7). Since g<4,
// g+4(t&1) == g^4(t&1): the layout change is a pure XOR inside the proven
// 8-granule swizzle, so bank distribution is bit-identical to the R0/R4
// layout (even 8-words/bank floor). LDS 32KB -> 16KB/block raises
// blocks/CU from 5 (LDS-limited) to ~7 (VGPR-limited): +40% resident waves
// for this latency/issue-bound kernel.
// launch_bounds(BS,4): 128-VGPR budget. NEVER request more waves/EU here:
// an earlier (,8) capped VGPR at 32 -> 1.2 GB scratch spill, 7x regression.
// LDS-weights + persistent blocks measured WORSE (51.5 µs, R3). Do not revisit.
__global__ __launch_bounds__(BS, 4) void nerf_main(const float* __restrict__ xin,
                                                   const uint4* __restrict__ wpack,
                                                   float* __restrict__ outp, int n) {
    // LDS only for input staging and the L2 color-input assembly.
    __shared__ __align__(16) char smem[NW * T * 1024];   // 16 KB
    const int tid = threadIdx.x, wv = tid >> 6, lane = tid & 63;
    const int p = lane & 15, q = lane >> 4;
    const int sw = p & 7;
    char* actw = smem + wv * (T * 1024);
    const int base = blockIdx.x * PTS_BLK + wv * (T * 16);

    // paired-tile swizzled address: tile t granule g (g in 0..3)
    auto aaddr = [&](int t, int g) -> char* {
        return actw + (t >> 1) * 2048 + p * 128 + (((g ^ ((t & 1) << 2)) ^ sw) << 4);
    };
    auto ldA = [&](int F) -> bf16x8 {
        uint4 u = wpack[F * 64 + lane];
        return *(bf16x8*)&u;
    };
    const f32x4 z4 = {0.f, 0.f, 0.f, 0.f};

    // D (4 m-tiles) -> pack+relu -> 4x v_permlane32_swap -> next layer's B frags.
    auto xpose = [&](const f32x4* d, bf16x8& b0, bf16x8& b1) {
        uint32_t X0 = pk2r(d[0][0], d[0][1]), X1 = pk2r(d[0][2], d[0][3]);
        uint32_t X2 = pk2r(d[1][0], d[1][1]), X3 = pk2r(d[1][2], d[1][3]);
        uint32_t X4 = pk2r(d[2][0], d[2][1]), X5 = pk2r(d[2][2], d[2][3]);
        uint32_t X6 = pk2r(d[3][0], d[3][1]), X7 = pk2r(d[3][2], d[3][3]);
        asm("v_permlane32_swap_b32 %0, %1" : "+v"(X0), "+v"(X4));
        asm("v_permlane32_swap_b32 %0, %1" : "+v"(X1), "+v"(X5));
        asm("v_permlane32_swap_b32 %0, %1" : "+v"(X2), "+v"(X6));
        asm("v_permlane32_swap_b32 %0, %1" : "+v"(X3), "+v"(X7));
        uint4 u0 = make_uint4(X0, X1, X2, X3), u1 = make_uint4(X4, X5, X6, X7);
        b0 = *(bf16x8*)&u0; b1 = *(bf16x8*)&u1;
    };

    // ---- staging: lane (p,q) stages tile q, point base+q*16+p ----
    float vv0 = 0.f, vv1 = 0.f, vv2 = 0.f;
    {
        float x0 = 0.f, x1 = 0.f, x2 = 0.f;
        const int pi = base + q * 16 + p;
        if (pi < n) {
            const float2* xp = (const float2*)(xin + (size_t)pi * 6);
            float2 a = xp[0], b = xp[1], c = xp[2];
            x0 = a.x; x1 = a.y; x2 = b.x; vv0 = b.y; vv1 = c.x; vv2 = c.y;
        }
        *(uint4*)aaddr(q, 0) = make_uint4(pk2(x0, x1), pk2(x2, 0.f), 0u, 0u);
        *(uint4*)aaddr(q, 1) = make_uint4(0u, 0u, 0u, 0u);
        *(uint4*)aaddr(q, 2) = make_uint4(0u, 0u, 0u, 0u);
        *(uint4*)aaddr(q, 3) = make_uint4(0u, 0u, 0u, 0u);
    }

    bf16x8 c0[T], c1[T];   // live activation fragments (register path)

    // K=32 LDS-fed layer (L0: ws0, L3: wc0) — per-tile xpose
    auto layerK32 = [&](int FB) {
        bf16x8 W0 = ldA(FB), W1 = ldA(FB + 1), W2 = ldA(FB + 2), W3 = ldA(FB + 3);
#pragma unroll
        for (int t = 0; t < T; ++t) {
            bf16x8 b = *(const bf16x8*)aaddr(t, q);
            f32x4 d[4];
            d[0] = __builtin_amdgcn_mfma_f32_16x16x32_bf16(W0, b, z4, 0, 0, 0);
            d[1] = __builtin_amdgcn_mfma_f32_16x16x32_bf16(W1, b, z4, 0, 0, 0);
            d[2] = __builtin_amdgcn_mfma_f32_16x16x32_bf16(W2, b, z4, 0, 0, 0);
            d[3] = __builtin_amdgcn_mfma_f32_16x16x32_bf16(W3, b, z4, 0, 0, 0);
            xpose(d, c0[t], c1[t]);
        }
    };

    // 64->64 register-fed layer — per-tile xpose, MFMA cluster under setprio
    auto layer64 = [&](int FB) {
        bf16x8 W[8];
#pragma unroll
        for (int i = 0; i < 8; ++i) W[i] = ldA(FB + i);
#pragma unroll
        for (int t = 0; t < T; ++t) {
            f32x4 d[4];
            __builtin_amdgcn_s_setprio(1);
#pragma unroll
            for (int mt = 0; mt < 4; ++mt) {
                f32x4 acc = __builtin_amdgcn_mfma_f32_16x16x32_bf16(W[mt*2],   c0[t], z4,  0, 0, 0);
                d[mt]     = __builtin_amdgcn_mfma_f32_16x16x32_bf16(W[mt*2+1], c1[t], acc, 0, 0, 0);
            }
            __builtin_amdgcn_s_setprio(0);
            xpose(d, c0[t], c1[t]);
        }
    };

    // ---- L0: sigma net 3->64 (frags 0..3), LDS-fed ----
    layerK32(0);

    // ---- L1: sigma net 64->64 (frags 4..11) ----
    layer64(4);

    // ---- L2: ws2 64->16 (frags 12,13): sigma + color-input assembly (LDS) ----
    float sig[T];
    {
        bf16x8 A0 = ldA(12), A1 = ldA(13);
#pragma unroll
        for (int t = 0; t < T; ++t) {
            f32x4 acc = __builtin_amdgcn_mfma_f32_16x16x32_bf16(A0, c0[t], z4,  0, 0, 0);
            f32x4 d   = __builtin_amdgcn_mfma_f32_16x16x32_bf16(A1, c1[t], acc, 0, 0, 0);
            const float sx = d[0];                       // feat0 valid on q==0 lanes
            sig[t] = fmaxf(sx, 0.f) + __logf(1.f + __expf(-fabsf(sx)));
            // zero granules 0..3 collectively, then scatter (plain s = k layout)
            *(uint4*)aaddr(t, q) = make_uint4(0u, 0u, 0u, 0u);
            if (q == t) {   // views of point p, tile t live on lane (p, t)
                *(uint32_t*)(aaddr(t, 0) + 0) = pk2(vv0, vv1);
                *(uint16_t*)(aaddr(t, 0) + 4) = bfu(vv2);
            }
            // geo feats f=4q+r (f>=1) -> color k=f+2
            if (q == 0) {
                *(uint16_t*)(aaddr(t, 0) + 6) = bfu(d[1]);
                *(uint32_t*)(aaddr(t, 0) + 8) = pk2(d[2], d[3]);
            } else if (q == 1) {
                *(uint32_t*)(aaddr(t, 0) + 12) = pk2(d[0], d[1]);
                *(uint32_t*)(aaddr(t, 1) + 0)  = pk2(d[2], d[3]);
            } else if (q == 2) {
                *(uint32_t*)(aaddr(t, 1) + 4) = pk2(d[0], d[1]);
                *(uint32_t*)(aaddr(t, 1) + 8) = pk2(d[2], d[3]);
            } else {
                *(uint32_t*)(aaddr(t, 1) + 12) = pk2(d[0], d[1]);
                *(uint32_t*)(aaddr(t, 2) + 0)  = pk2(d[2], d[3]);
            }
        }
    }

    // ---- L3: wc0 18->64 (frags 14..17), LDS-fed ----
    layerK32(14);

    // ---- L4, L5: wc1, wc2 64->64 ----
    layer64(18);
    layer64(26);

    // ---- L6: wc3 64->3 (frags 34,35) + output ----
    {
        bf16x8 A0 = ldA(34), A1 = ldA(35);
#pragma unroll
        for (int t = 0; t < T; ++t) {
            f32x4 acc = __builtin_amdgcn_mfma_f32_16x16x32_bf16(A0, c0[t], z4,  0, 0, 0);
            f32x4 d   = __builtin_amdgcn_mfma_f32_16x16x32_bf16(A1, c1[t], acc, 0, 0, 0);
            if (q == 0) {
                const int pt = base + t * 16 + p;
                if (pt < n)
                    *(float4*)(outp + (size_t)pt * 4) = make_float4(d[0], d[1], d[2], sig[t]);
            }
        }
    }
}

extern "C" void kernel_launch(void* const* d_in, const int* in_sizes, int n_in,
                              void* d_out, int out_size, void* d_ws, size_t ws_size,
                              hipStream_t stream) {
    const float* x   = (const float*)d_in[0];
    const float* ws0 = (const float*)d_in[1];
    const float* ws1 = (const float*)d_in[2];
    const float* ws2 = (const float*)d_in[3];
    const float* wc0 = (const float*)d_in[4];
    const float* wc1 = (const float*)d_in[5];
    const float* wc2 = (const float*)d_in[6];
    const float* wc3 = (const float*)d_in[7];
    float* out = (float*)d_out;
    uint4* wpack = (uint4*)d_ws;

    const int n = in_sizes[0] / 6;
    pack_weights<<<(NFRAGS * 64 + 255) / 256, 256, 0, stream>>>(ws0, ws1, ws2, wc0, wc1, wc2, wc3, wpack);
    const int grid = (n + PTS_BLK - 1) / PTS_BLK;
    nerf_main<<<grid, BS, 0, stream>>>(x, wpack, out, n);
}